// Round 3
// baseline (209.047 us; speedup 1.0000x reference)
//
#include <hip/hip_runtime.h>
#include <hip/hip_bf16.h>

#define NPIX 9216
#define SPLIT 4
#define MTILES (NPIX / 16)             // 576
#define NB_PER_BLOCK (NPIX / SPLIT)    // 2304
#define NB_PER_WAVE (NB_PER_BLOCK / 4) // 576
#define TILES_PER_WAVE (NB_PER_WAVE / 32) // 18

typedef __attribute__((ext_vector_type(4))) float f32x4;
typedef __attribute__((ext_vector_type(8))) short bf16x8;
typedef __attribute__((ext_vector_type(2))) unsigned int u32x2;

// ---------------- Kernel 1: spectral norm sigmas (1 block, 64 threads) ------
__global__ void spectral_kernel(const float* __restrict__ Wf, const float* __restrict__ Wg,
                                const float* __restrict__ Wh, const float* __restrict__ uf,
                                const float* __restrict__ ug, const float* __restrict__ uh,
                                float* __restrict__ inv_sigma) {
  __shared__ float vsh[64];
  const int t = threadIdx.x;  // 0..63, one wave
  for (int widx = 0; widx < 3; ++widx) {
    const float* W = (widx == 0) ? Wf : (widx == 1) ? Wg : Wh;
    const float* u = (widx == 0) ? uf : (widx == 1) ? ug : uh;
    const int O = (widx == 2) ? 64 : 8;
    float v = 0.f;
    for (int o = 0; o < O; ++o) v += W[o * 64 + t] * u[o];
    float s = v * v;
    for (int off = 32; off; off >>= 1) s += __shfl_xor(s, off);
    const float vn = v / (sqrtf(s) + 1e-12f);
    vsh[t] = vn;
    __syncthreads();
    float wv = 0.f;
    if (t < O) { for (int c = 0; c < 64; ++c) wv += W[t * 64 + c] * vsh[c]; }
    float s2 = (t < O) ? wv * wv : 0.f;
    for (int off = 32; off; off >>= 1) s2 += __shfl_xor(s2, off);
    const float nw = sqrtf(s2);
    const float sigma = s2 / (nw + 1e-12f);
    if (t == 0) inv_sigma[widx] = 1.f / sigma;
    __syncthreads();
  }
}

// ---------------- Kernel 2: f,g,h projections --------------------------------
// Qp : [NPIX][16] bf16  (qh[0..7], ql[0..7]) of (f-value * 0.25)   [hi/lo split]
// Kp : [NPIX][16] bf16  (kh[0..7], kl[0..7]) of g-value            [hi/lo split]
// Vt : [64][NPIX] bf16  (h natural layout)
__global__ __launch_bounds__(256) void fgh_kernel(
    const float* __restrict__ x,
    const float* __restrict__ Wf, const float* __restrict__ bf,
    const float* __restrict__ Wg, const float* __restrict__ bg,
    const float* __restrict__ Wh, const float* __restrict__ bh,
    const float* __restrict__ inv_sigma,
    ushort* __restrict__ Qp, ushort* __restrict__ Kp, ushort* __restrict__ Vt) {
  const int p = blockIdx.x * 256 + threadIdx.x;   // pixel
  const int by = blockIdx.y;                      // rows 4*by .. 4*by+3 of 80
  const float* Wp[4]; const float* bp[4]; float isv[4]; int ro[4];
  #pragma unroll
  for (int rr = 0; rr < 4; ++rr) {
    const int r = by * 4 + rr;
    if (r < 8)       { Wp[rr] = Wf; bp[rr] = bf; isv[rr] = inv_sigma[0]; ro[rr] = r; }
    else if (r < 16) { Wp[rr] = Wg; bp[rr] = bg; isv[rr] = inv_sigma[1]; ro[rr] = r - 8; }
    else             { Wp[rr] = Wh; bp[rr] = bh; isv[rr] = inv_sigma[2]; ro[rr] = r - 16; }
  }
  float a[4] = {0.f, 0.f, 0.f, 0.f};
  for (int c = 0; c < 64; ++c) {
    const float xv = x[c * NPIX + p];
    #pragma unroll
    for (int rr = 0; rr < 4; ++rr) a[rr] += Wp[rr][ro[rr] * 64 + c] * xv;
  }
  #pragma unroll
  for (int rr = 0; rr < 4; ++rr) {
    const int r = by * 4 + rr;
    const float val = a[rr] * isv[rr] + bp[rr][ro[rr]];
    if (r < 8) {
      const float vq = val * 0.25f;  // exact: folds the K-broadcast /4
      const __hip_bfloat16 h = __float2bfloat16(vq);
      const float hf = __bfloat162float(h);
      const __hip_bfloat16 lo = __float2bfloat16(vq - hf);
      Qp[p * 16 + r]     = *(const ushort*)&h;
      Qp[p * 16 + 8 + r] = *(const ushort*)&lo;
    } else if (r < 16) {
      const __hip_bfloat16 h = __float2bfloat16(val);
      const float hf = __bfloat162float(h);
      const __hip_bfloat16 lo = __float2bfloat16(val - hf);
      Kp[p * 16 + (r - 8)]     = *(const ushort*)&h;
      Kp[p * 16 + 8 + (r - 8)] = *(const ushort*)&lo;
    } else {
      const __hip_bfloat16 hv = __float2bfloat16(val);
      Vt[(r - 16) * NPIX + p] = *(const ushort*)&hv;
    }
  }
}

// ---------------- Kernel 3a: flash attention, MFMA S^T, split-n --------------
// Grid: (MTILES, SPLIT). Block: 16 query rows, 4 waves split the n-range.
// S^T tile via mfma(K_frag, Q_frag): lane l holds 8 S values of row m=l&15 at
// n-offsets {4g..4g+3, 16+4g..16+4g+3} (g=l>>4) -> exp'd values are already in
// the PV A-frag slot order (kslot = 8g+4t+i <-> n-offset 16t+4g+i), matched by
// the V B-frag gather. K rows broadcast to all 4 k-groups; 1/4 folded into Q.
// Precision: S = Kh*qh + Kh*ql + Kl*qh (hi/lo bf16 split) ~= f32-exact.
__global__ __launch_bounds__(256) void attn_kernel(
    const ushort* __restrict__ Qp, const ushort* __restrict__ Kp,
    const ushort* __restrict__ Vt,
    float* __restrict__ Om,   // [MTILES][SPLIT][1024]  (e = c*16+m)
    float* __restrict__ Sm) { // [MTILES][SPLIT][32]    (16 mx, 16 ls)
  __shared__ float O_s[4][16][65];
  __shared__ float mx_s[4][16];
  __shared__ float ls_s[4][16];
  const int tid  = threadIdx.x;
  const int w    = tid >> 6;
  const int l    = tid & 63;
  const int mloc = l & 15;
  const int g    = l >> 4;
  const int m0   = blockIdx.x * 16;
  const int spl  = blockIdx.y;

  const bf16x8 qh = *(const bf16x8*)(Qp + (m0 + mloc) * 16);
  const bf16x8 ql = *(const bf16x8*)(Qp + (m0 + mloc) * 16 + 8);

  float mx = -INFINITY, ls = 0.f;
  const f32x4 zero = {0.f, 0.f, 0.f, 0.f};
  f32x4 acc0 = zero, acc1 = zero, acc2 = zero, acc3 = zero;
  const int n_begin = spl * NB_PER_BLOCK + w * NB_PER_WAVE;

  for (int it = 0; it < TILES_PER_WAVE; ++it) {
    const int nb = n_begin + it * 32;
    // ---- S^T = K . Q^T  (2 n-subtiles x 3 hi/lo MFMAs) ----
    const ushort* kr = Kp + (nb + mloc) * 16;
    const bf16x8 kh0 = *(const bf16x8*)(kr);
    const bf16x8 kl0 = *(const bf16x8*)(kr + 8);
    const bf16x8 kh1 = *(const bf16x8*)(kr + 256);
    const bf16x8 kl1 = *(const bf16x8*)(kr + 264);
    f32x4 s0 = zero, s1 = zero;
    s0 = __builtin_amdgcn_mfma_f32_16x16x32_bf16(kh0, qh, s0, 0, 0, 0);
    s1 = __builtin_amdgcn_mfma_f32_16x16x32_bf16(kh1, qh, s1, 0, 0, 0);
    s0 = __builtin_amdgcn_mfma_f32_16x16x32_bf16(kh0, ql, s0, 0, 0, 0);
    s1 = __builtin_amdgcn_mfma_f32_16x16x32_bf16(kh1, ql, s1, 0, 0, 0);
    s0 = __builtin_amdgcn_mfma_f32_16x16x32_bf16(kl0, qh, s0, 0, 0, 0);
    s1 = __builtin_amdgcn_mfma_f32_16x16x32_bf16(kl1, qh, s1, 0, 0, 0);
    // ---- online softmax over the 32-n tile (row m = l&15) ----
    float tm = fmaxf(fmaxf(fmaxf(s0[0], s0[1]), fmaxf(s0[2], s0[3])),
                     fmaxf(fmaxf(s1[0], s1[1]), fmaxf(s1[2], s1[3])));
    tm = fmaxf(tm, __shfl_xor(tm, 16));
    tm = fmaxf(tm, __shfl_xor(tm, 32));
    if (__any(tm > mx + 8.0f)) {  // defer-max: rescale only on big jumps
      const float mxn = fmaxf(mx, tm);
      const float corr = __expf(mx - mxn);
      ls *= corr;
      const float c0 = __shfl(corr, (g << 2) + 0);
      const float c1 = __shfl(corr, (g << 2) + 1);
      const float c2 = __shfl(corr, (g << 2) + 2);
      const float c3 = __shfl(corr, (g << 2) + 3);
      acc0[0] *= c0; acc0[1] *= c1; acc0[2] *= c2; acc0[3] *= c3;
      acc1[0] *= c0; acc1[1] *= c1; acc1[2] *= c2; acc1[3] *= c3;
      acc2[0] *= c0; acc2[1] *= c1; acc2[2] *= c2; acc2[3] *= c3;
      acc3[0] *= c0; acc3[1] *= c1; acc3[2] *= c2; acc3[3] *= c3;
      mx = mxn;
    }
    float pj[8];
    pj[0] = __expf(s0[0] - mx); pj[1] = __expf(s0[1] - mx);
    pj[2] = __expf(s0[2] - mx); pj[3] = __expf(s0[3] - mx);
    pj[4] = __expf(s1[0] - mx); pj[5] = __expf(s1[1] - mx);
    pj[6] = __expf(s1[2] - mx); pj[7] = __expf(s1[3] - mx);
    float ps = ((pj[0] + pj[1]) + (pj[2] + pj[3])) + ((pj[4] + pj[5]) + (pj[6] + pj[7]));
    ps += __shfl_xor(ps, 16);
    ps += __shfl_xor(ps, 32);
    ls += ps;
    // ---- pack P to bf16 A-frag (slot e=4t+i) ----
    union { unsigned int u[4]; bf16x8 v; } pu;
    #pragma unroll
    for (int j = 0; j < 4; ++j) {
      unsigned int r;
      asm("v_cvt_pk_bf16_f32 %0, %1, %2" : "=v"(r) : "v"(pj[2 * j]), "v"(pj[2 * j + 1]));
      pu.u[j] = r;
    }
    // ---- PV: B-frag gather V rows nb+4g..+3 and nb+16+4g..+3, col=c ----
    #pragma unroll
    for (int ct = 0; ct < 4; ++ct) {
      const ushort* vb = Vt + (ct * 16 + mloc) * NPIX + nb + 4 * g;
      const u32x2 va = *(const u32x2*)(vb);
      const u32x2 vc = *(const u32x2*)(vb + 16);
      union { unsigned int u[4]; bf16x8 v; } vv;
      vv.u[0] = va[0]; vv.u[1] = va[1]; vv.u[2] = vc[0]; vv.u[3] = vc[1];
      if (ct == 0) acc0 = __builtin_amdgcn_mfma_f32_16x16x32_bf16(pu.v, vv.v, acc0, 0, 0, 0);
      if (ct == 1) acc1 = __builtin_amdgcn_mfma_f32_16x16x32_bf16(pu.v, vv.v, acc1, 0, 0, 0);
      if (ct == 2) acc2 = __builtin_amdgcn_mfma_f32_16x16x32_bf16(pu.v, vv.v, acc2, 0, 0, 0);
      if (ct == 3) acc3 = __builtin_amdgcn_mfma_f32_16x16x32_bf16(pu.v, vv.v, acc3, 0, 0, 0);
    }
  }

  if (l < 16) { mx_s[w][l] = mx; ls_s[w][l] = ls; }
  #pragma unroll
  for (int i = 0; i < 4; ++i) {
    const int r = g * 4 + i;  // C-frag row = output m-row
    O_s[w][r][mloc]      = acc0[i];
    O_s[w][r][16 + mloc] = acc1[i];
    O_s[w][r][32 + mloc] = acc2[i];
    O_s[w][r][48 + mloc] = acc3[i];
  }
  __syncthreads();
  // merge 4 waves -> un-normalized partial for this split
  float* Ob = Om + (blockIdx.x * SPLIT + spl) * 1024;
  float* Sb = Sm + (blockIdx.x * SPLIT + spl) * 32;
  for (int e = tid; e < 1024; e += 256) {
    const int m = e & 15, c = e >> 4;
    const float ma = mx_s[0][m], mb = mx_s[1][m], mc = mx_s[2][m], md = mx_s[3][m];
    const float M = fmaxf(fmaxf(ma, mb), fmaxf(mc, md));
    const float e0 = __expf(ma - M), e1 = __expf(mb - M), e2 = __expf(mc - M), e3 = __expf(md - M);
    const float val = O_s[0][m][c] * e0 + O_s[1][m][c] * e1 + O_s[2][m][c] * e2 + O_s[3][m][c] * e3;
    Ob[e] = val;
  }
  if (tid < 16) {
    const int m = tid;
    const float ma = mx_s[0][m], mb = mx_s[1][m], mc = mx_s[2][m], md = mx_s[3][m];
    const float M = fmaxf(fmaxf(ma, mb), fmaxf(mc, md));
    const float L = ls_s[0][m] * __expf(ma - M) + ls_s[1][m] * __expf(mb - M)
                  + ls_s[2][m] * __expf(mc - M) + ls_s[3][m] * __expf(md - M);
    Sb[m]      = M;
    Sb[16 + m] = L;
  }
}

// ---------------- Kernel 3b: combine split partials --------------------------
__global__ __launch_bounds__(256) void combine_kernel(
    const float* __restrict__ Om, const float* __restrict__ Sm,
    const float* __restrict__ x, const float* __restrict__ gammap,
    float* __restrict__ out) {
  const int mt = blockIdx.x;
  const int m0 = mt * 16;
  const float gamma = gammap[0];
  const float* Sb = Sm + mt * SPLIT * 32;
  const float* Ob = Om + mt * SPLIT * 1024;
  for (int e = threadIdx.x; e < 1024; e += 256) {
    const int m = e & 15, c = e >> 4;
    float M = -INFINITY;
    #pragma unroll
    for (int s = 0; s < SPLIT; ++s) M = fmaxf(M, Sb[s * 32 + m]);
    float L = 0.f, val = 0.f;
    #pragma unroll
    for (int s = 0; s < SPLIT; ++s) {
      const float ws = __expf(Sb[s * 32 + m] - M);
      L   += Sb[s * 32 + 16 + m] * ws;
      val += Ob[s * 1024 + e] * ws;
    }
    const int idx = c * NPIX + m0 + m;
    out[idx] = gamma * (val / L) + x[idx];
  }
}

// ---------------- launcher ---------------------------------------------------
extern "C" void kernel_launch(void* const* d_in, const int* in_sizes, int n_in,
                              void* d_out, int out_size, void* d_ws, size_t ws_size,
                              hipStream_t stream) {
  const float* x     = (const float*)d_in[0];
  const float* Wf    = (const float*)d_in[1];
  const float* bf    = (const float*)d_in[2];
  const float* Wg    = (const float*)d_in[3];
  const float* bg    = (const float*)d_in[4];
  const float* Wh    = (const float*)d_in[5];
  const float* bh    = (const float*)d_in[6];
  const float* gamma = (const float*)d_in[7];
  const float* uf    = (const float*)d_in[8];
  const float* ug    = (const float*)d_in[9];
  const float* uh    = (const float*)d_in[10];
  float* out = (float*)d_out;

  char* ws = (char*)d_ws;
  float*  inv_sigma = (float*)ws;                                   // 12 B
  ushort* Qp = (ushort*)(ws + 256);                                 // 294912 B
  ushort* Kp = (ushort*)(ws + 256 + NPIX * 16 * 2);                 // 294912 B
  ushort* Vt = (ushort*)(ws + 256 + 2 * NPIX * 16 * 2);             // 1179648 B
  size_t off = 256 + (size_t)2 * NPIX * 16 * 2 + (size_t)NPIX * 64 * 2;
  float* Om = (float*)(ws + off);                                   // 9437184 B
  float* Sm = (float*)(ws + off + (size_t)MTILES * SPLIT * 1024 * 4); // 294912 B

  spectral_kernel<<<1, 64, 0, stream>>>(Wf, Wg, Wh, uf, ug, uh, inv_sigma);
  fgh_kernel<<<dim3(NPIX / 256, 20), 256, 0, stream>>>(x, Wf, bf, Wg, bg, Wh, bh,
                                                       inv_sigma, Qp, Kp, Vt);
  attn_kernel<<<dim3(MTILES, SPLIT), 256, 0, stream>>>(Qp, Kp, Vt, Om, Sm);
  combine_kernel<<<MTILES, 256, 0, stream>>>(Om, Sm, x, gamma, out);
}

// Round 4
// 92.004 us; speedup vs baseline: 2.2722x; 2.2722x over previous
//
#include <hip/hip_runtime.h>
#include <hip/hip_bf16.h>

#define NPIX 9216
#define SPLIT 8
#define NSEG (NPIX / SPLIT)   // 1152 n per block
#define NT (NSEG / 32)        // 36 tiles
#define MTILES (NPIX / 16)    // 576

typedef __attribute__((ext_vector_type(4))) float f32x4;
typedef __attribute__((ext_vector_type(8))) short bf16x8;
typedef __attribute__((ext_vector_type(2))) unsigned int u32x2;

__device__ __forceinline__ void gload_lds16(const void* g, void* l) {
  __builtin_amdgcn_global_load_lds(
      (const __attribute__((address_space(1))) unsigned int*)g,
      (__attribute__((address_space(3))) unsigned int*)l, 16, 0, 0);
}

// ---------------- Kernel 1: spectral norm sigmas (1 block, 64 threads) ------
__global__ void spectral_kernel(const float* __restrict__ Wf, const float* __restrict__ Wg,
                                const float* __restrict__ Wh, const float* __restrict__ uf,
                                const float* __restrict__ ug, const float* __restrict__ uh,
                                float* __restrict__ inv_sigma) {
  __shared__ float vsh[64];
  const int t = threadIdx.x;
  for (int widx = 0; widx < 3; ++widx) {
    const float* W = (widx == 0) ? Wf : (widx == 1) ? Wg : Wh;
    const float* u = (widx == 0) ? uf : (widx == 1) ? ug : uh;
    const int O = (widx == 2) ? 64 : 8;
    float v = 0.f;
    for (int o = 0; o < O; ++o) v += W[o * 64 + t] * u[o];
    float s = v * v;
    for (int off = 32; off; off >>= 1) s += __shfl_xor(s, off);
    const float vn = v / (sqrtf(s) + 1e-12f);
    vsh[t] = vn;
    __syncthreads();
    float wv = 0.f;
    if (t < O) { for (int c = 0; c < 64; ++c) wv += W[t * 64 + c] * vsh[c]; }
    float s2 = (t < O) ? wv * wv : 0.f;
    for (int off = 32; off; off >>= 1) s2 += __shfl_xor(s2, off);
    const float nw = sqrtf(s2);
    const float sigma = s2 / (nw + 1e-12f);
    if (t == 0) inv_sigma[widx] = 1.f / sigma;
    __syncthreads();
  }
}

// ---------------- Kernel 2: f,g,h projections --------------------------------
// Qp  : [NPIX][16] bf16  (qh[0..7], ql[0..7]) of (f * 0.25)  [hi/lo split]
// Kp  : [NPIX][16] bf16  (kh[0..7], kl[0..7]) of g           [hi/lo split]
// Vt2 : [288 tiles][8 j][64 c][4 i] bf16 — tile-contiguous 4KB blocks in
//        the exact LDS staging order; (c, n) lives at tile=n>>5, j=(n&31)>>2,
//        i=n&3 -> ushort idx tile*2048 + j*256 + c*4 + i.
// Grid (36, 5): by==0 -> f+g rows; by 1..4 -> h rows (by-1)*16..+15.
__global__ __launch_bounds__(256) void fgh_kernel(
    const float* __restrict__ x,
    const float* __restrict__ Wf, const float* __restrict__ bfv,
    const float* __restrict__ Wg, const float* __restrict__ bgv,
    const float* __restrict__ Wh, const float* __restrict__ bhv,
    const float* __restrict__ inv_sigma,
    ushort* __restrict__ Qp, ushort* __restrict__ Kp, ushort* __restrict__ Vt2) {
  const int p = blockIdx.x * 256 + threadIdx.x;
  const int by = blockIdx.y;
  float xv[64];
  #pragma unroll
  for (int c = 0; c < 64; ++c) xv[c] = x[c * NPIX + p];

  if (by == 0) {
    const float isf = inv_sigma[0], isg = inv_sigma[1];
    for (int r = 0; r < 8; ++r) {
      float a = 0.f;
      #pragma unroll
      for (int c = 0; c < 64; ++c) a += Wf[r * 64 + c] * xv[c];
      const float vq = (a * isf + bfv[r]) * 0.25f;  // folds K-broadcast /4
      const __hip_bfloat16 h = __float2bfloat16(vq);
      const float hf = __bfloat162float(h);
      const __hip_bfloat16 lo = __float2bfloat16(vq - hf);
      Qp[p * 16 + r]     = *(const ushort*)&h;
      Qp[p * 16 + 8 + r] = *(const ushort*)&lo;
    }
    for (int r = 0; r < 8; ++r) {
      float a = 0.f;
      #pragma unroll
      for (int c = 0; c < 64; ++c) a += Wg[r * 64 + c] * xv[c];
      const float val = a * isg + bgv[r];
      const __hip_bfloat16 h = __float2bfloat16(val);
      const float hf = __bfloat162float(h);
      const __hip_bfloat16 lo = __float2bfloat16(val - hf);
      Kp[p * 16 + r]     = *(const ushort*)&h;
      Kp[p * 16 + 8 + r] = *(const ushort*)&lo;
    }
  } else {
    const float ish = inv_sigma[2];
    const int tile = p >> 5, j = (p & 31) >> 2, i = p & 3;
    ushort* vout = Vt2 + (size_t)tile * 2048 + j * 256 + i;
    const int rbase = (by - 1) * 16;
    for (int rr = 0; rr < 16; ++rr) {
      const int r = rbase + rr;
      float a = 0.f;
      #pragma unroll
      for (int c = 0; c < 64; ++c) a += Wh[r * 64 + c] * xv[c];
      const float val = a * ish + bhv[r];
      const __hip_bfloat16 hv = __float2bfloat16(val);
      vout[r * 4] = *(const ushort*)&hv;
    }
  }
}

// ---------------- Kernel 3a: flash attention, m-shared LDS-staged ------------
// Grid (144, SPLIT). Block = 64 m-rows: wave w owns m-rows bx*64+w*16..+15.
// All 4 waves walk the same n-range; K (1KB) + V (4KB) staged to LDS via
// global_load_lds, double-buffered, one barrier per 32-n tile.
// S^T via mfma(K,Q) hi/lo as R2 (verified); PV B-frags ds_read from Vs.
__global__ __launch_bounds__(256) void attn_kernel(
    const ushort* __restrict__ Qp, const ushort* __restrict__ Kp,
    const ushort* __restrict__ Vt2,
    ushort* __restrict__ Om,   // [576 mt][SPLIT][1024] bf16 (e = c*16 + m)
    float* __restrict__ Sm) {  // [576 mt][SPLIT][32]  f32 (16 mx, 16 ls)
  __shared__ ushort Vs[2][2048];  // [j 0..7][c 0..63][i 0..3]
  __shared__ ushort Ks[2][512];   // [n 0..31][16] (kh8, kl8)
  const int tid  = threadIdx.x;
  const int w    = tid >> 6;
  const int l    = tid & 63;
  const int mloc = l & 15;
  const int g    = l >> 4;
  const int spl  = blockIdx.y;
  const int mrow = blockIdx.x * 64 + w * 16 + mloc;

  const bf16x8 qh = *(const bf16x8*)(Qp + mrow * 16);
  const bf16x8 ql = *(const bf16x8*)(Qp + mrow * 16 + 8);

  const int n0 = spl * NSEG;
  const ushort* vsrc = Vt2 + (size_t)(n0 >> 5) * 2048 + w * 512 + l * 8;
  const ushort* ksrc = Kp + (size_t)n0 * 16 + l * 8;

  gload_lds16(vsrc, &Vs[0][w * 512]);
  if (w == 0) gload_lds16(ksrc, &Ks[0][0]);
  __syncthreads();

  float mx = -INFINITY, ls = 0.f;
  const f32x4 zero = {0.f, 0.f, 0.f, 0.f};
  f32x4 acc0 = zero, acc1 = zero, acc2 = zero, acc3 = zero;
  int buf = 0;

  for (int t = 0; t < NT; ++t) {
    if (t + 1 < NT) {
      gload_lds16(vsrc + (size_t)(t + 1) * 2048, &Vs[buf ^ 1][w * 512]);
      if (w == 0) gload_lds16(ksrc + (size_t)(t + 1) * 512, &Ks[buf ^ 1][0]);
    }
    // ---- S^T = K . Q^T (2 n-subtiles x 3 hi/lo MFMAs) ----
    const ushort* kb = &Ks[buf][0];
    const bf16x8 kh0 = *(const bf16x8*)(kb + mloc * 16);
    const bf16x8 kl0 = *(const bf16x8*)(kb + mloc * 16 + 8);
    const bf16x8 kh1 = *(const bf16x8*)(kb + (16 + mloc) * 16);
    const bf16x8 kl1 = *(const bf16x8*)(kb + (16 + mloc) * 16 + 8);
    f32x4 s0 = zero, s1 = zero;
    s0 = __builtin_amdgcn_mfma_f32_16x16x32_bf16(kh0, qh, s0, 0, 0, 0);
    s1 = __builtin_amdgcn_mfma_f32_16x16x32_bf16(kh1, qh, s1, 0, 0, 0);
    s0 = __builtin_amdgcn_mfma_f32_16x16x32_bf16(kh0, ql, s0, 0, 0, 0);
    s1 = __builtin_amdgcn_mfma_f32_16x16x32_bf16(kh1, ql, s1, 0, 0, 0);
    s0 = __builtin_amdgcn_mfma_f32_16x16x32_bf16(kl0, qh, s0, 0, 0, 0);
    s1 = __builtin_amdgcn_mfma_f32_16x16x32_bf16(kl1, qh, s1, 0, 0, 0);
    // ---- online softmax (row m = mloc) ----
    float tm = fmaxf(fmaxf(fmaxf(s0[0], s0[1]), fmaxf(s0[2], s0[3])),
                     fmaxf(fmaxf(s1[0], s1[1]), fmaxf(s1[2], s1[3])));
    tm = fmaxf(tm, __shfl_xor(tm, 16));
    tm = fmaxf(tm, __shfl_xor(tm, 32));
    if (__any(tm > mx + 8.0f)) {  // defer-max
      const float mxn = fmaxf(mx, tm);
      const float corr = __expf(mx - mxn);
      ls *= corr;
      const float c0 = __shfl(corr, (g << 2) + 0);
      const float c1 = __shfl(corr, (g << 2) + 1);
      const float c2 = __shfl(corr, (g << 2) + 2);
      const float c3 = __shfl(corr, (g << 2) + 3);
      acc0[0] *= c0; acc0[1] *= c1; acc0[2] *= c2; acc0[3] *= c3;
      acc1[0] *= c0; acc1[1] *= c1; acc1[2] *= c2; acc1[3] *= c3;
      acc2[0] *= c0; acc2[1] *= c1; acc2[2] *= c2; acc2[3] *= c3;
      acc3[0] *= c0; acc3[1] *= c1; acc3[2] *= c2; acc3[3] *= c3;
      mx = mxn;
    }
    float pj[8];
    pj[0] = __expf(s0[0] - mx); pj[1] = __expf(s0[1] - mx);
    pj[2] = __expf(s0[2] - mx); pj[3] = __expf(s0[3] - mx);
    pj[4] = __expf(s1[0] - mx); pj[5] = __expf(s1[1] - mx);
    pj[6] = __expf(s1[2] - mx); pj[7] = __expf(s1[3] - mx);
    float ps = ((pj[0] + pj[1]) + (pj[2] + pj[3])) + ((pj[4] + pj[5]) + (pj[6] + pj[7]));
    ps += __shfl_xor(ps, 16);
    ps += __shfl_xor(ps, 32);
    ls += ps;
    union { unsigned int u[4]; bf16x8 v; } pu;
    #pragma unroll
    for (int jj = 0; jj < 4; ++jj) {
      unsigned int r;
      asm("v_cvt_pk_bf16_f32 %0, %1, %2" : "=v"(r) : "v"(pj[2 * jj]), "v"(pj[2 * jj + 1]));
      pu.u[jj] = r;
    }
    // ---- PV from LDS: unit (c, j) at ushort idx j*256 + c*4 ----
    const ushort* vb = &Vs[buf][0];
    #pragma unroll
    for (int ct = 0; ct < 4; ++ct) {
      const int vbase = g * 256 + (ct * 16 + mloc) * 4;
      const u32x2 va = *(const u32x2*)(vb + vbase);          // j = g
      const u32x2 vc = *(const u32x2*)(vb + vbase + 1024);   // j = 4 + g
      union { unsigned int u[4]; bf16x8 v; } vv;
      vv.u[0] = va[0]; vv.u[1] = va[1]; vv.u[2] = vc[0]; vv.u[3] = vc[1];
      if (ct == 0) acc0 = __builtin_amdgcn_mfma_f32_16x16x32_bf16(pu.v, vv.v, acc0, 0, 0, 0);
      if (ct == 1) acc1 = __builtin_amdgcn_mfma_f32_16x16x32_bf16(pu.v, vv.v, acc1, 0, 0, 0);
      if (ct == 2) acc2 = __builtin_amdgcn_mfma_f32_16x16x32_bf16(pu.v, vv.v, acc2, 0, 0, 0);
      if (ct == 3) acc3 = __builtin_amdgcn_mfma_f32_16x16x32_bf16(pu.v, vv.v, acc3, 0, 0, 0);
    }
    __syncthreads();
    buf ^= 1;
  }

  // ---- write un-normalized partials (wave-local; no cross-wave merge) ----
  const size_t mt = (size_t)blockIdx.x * 4 + w;
  ushort* Ob = Om + (mt * SPLIT + spl) * 1024;
  float*  Sb = Sm + (mt * SPLIT + spl) * 32;
  #pragma unroll
  for (int ct = 0; ct < 4; ++ct) {
    const f32x4 a = (ct == 0) ? acc0 : (ct == 1) ? acc1 : (ct == 2) ? acc2 : acc3;
    unsigned int r0, r1;
    asm("v_cvt_pk_bf16_f32 %0, %1, %2" : "=v"(r0) : "v"(a[0]), "v"(a[1]));
    asm("v_cvt_pk_bf16_f32 %0, %1, %2" : "=v"(r1) : "v"(a[2]), "v"(a[3]));
    u32x2 pk; pk[0] = r0; pk[1] = r1;
    *(u32x2*)(Ob + (ct * 16 + mloc) * 16 + 4 * g) = pk;  // e = c*16 + (4g+i)
  }
  if (l < 16) { Sb[l] = mx; Sb[16 + l] = ls; }
}

// ---------------- Kernel 3b: combine split partials --------------------------
__global__ __launch_bounds__(256) void combine_kernel(
    const ushort* __restrict__ Om, const float* __restrict__ Sm,
    const float* __restrict__ x, const float* __restrict__ gammap,
    float* __restrict__ out) {
  const int mt = blockIdx.x;
  const int m0 = mt * 16;
  const float gamma = gammap[0];
  const float* Sb = Sm + (size_t)mt * SPLIT * 32;
  const ushort* Ob = Om + (size_t)mt * SPLIT * 1024;
  for (int e = threadIdx.x; e < 1024; e += 256) {
    const int m = e & 15, c = e >> 4;
    float M = -INFINITY;
    #pragma unroll
    for (int s = 0; s < SPLIT; ++s) M = fmaxf(M, Sb[s * 32 + m]);
    float L = 0.f, val = 0.f;
    #pragma unroll
    for (int s = 0; s < SPLIT; ++s) {
      const float wgt = __expf(Sb[s * 32 + m] - M);
      L += Sb[s * 32 + 16 + m] * wgt;
      union { unsigned int i; float f; } cv;
      cv.i = ((unsigned int)Ob[s * 1024 + e]) << 16;
      val += cv.f * wgt;
    }
    const int idx = c * NPIX + m0 + m;
    out[idx] = gamma * (val / L) + x[idx];
  }
}

// ---------------- launcher ---------------------------------------------------
extern "C" void kernel_launch(void* const* d_in, const int* in_sizes, int n_in,
                              void* d_out, int out_size, void* d_ws, size_t ws_size,
                              hipStream_t stream) {
  const float* x     = (const float*)d_in[0];
  const float* Wf    = (const float*)d_in[1];
  const float* bf    = (const float*)d_in[2];
  const float* Wg    = (const float*)d_in[3];
  const float* bg    = (const float*)d_in[4];
  const float* Wh    = (const float*)d_in[5];
  const float* bh    = (const float*)d_in[6];
  const float* gamma = (const float*)d_in[7];
  const float* uf    = (const float*)d_in[8];
  const float* ug    = (const float*)d_in[9];
  const float* uh    = (const float*)d_in[10];
  float* out = (float*)d_out;

  char* ws = (char*)d_ws;
  float*  inv_sigma = (float*)ws;                                    // 12 B
  ushort* Qp  = (ushort*)(ws + 256);                                 // 294912 B
  ushort* Kp  = (ushort*)(ws + 256 + NPIX * 16 * 2);                 // 294912 B
  ushort* Vt2 = (ushort*)(ws + 256 + 2 * NPIX * 16 * 2);             // 1179648 B
  size_t off = 256 + (size_t)2 * NPIX * 16 * 2 + (size_t)NPIX * 64 * 2;
  ushort* Om = (ushort*)(ws + off);                                  // 9437184 B
  float*  Sm = (float*)(ws + off + (size_t)MTILES * SPLIT * 1024 * 2); // 589824 B

  spectral_kernel<<<1, 64, 0, stream>>>(Wf, Wg, Wh, uf, ug, uh, inv_sigma);
  fgh_kernel<<<dim3(NPIX / 256, 5), 256, 0, stream>>>(x, Wf, bf, Wg, bg, Wh, bh,
                                                      inv_sigma, Qp, Kp, Vt2);
  attn_kernel<<<dim3(NPIX / 64, SPLIT), 256, 0, stream>>>(Qp, Kp, Vt2, Om, Sm);
  combine_kernel<<<MTILES, 256, 0, stream>>>(Om, Sm, x, gamma, out);
}